// Round 3
// baseline (425.561 us; speedup 1.0000x reference)
//
#include <hip/hip_runtime.h>
#include <hip/hip_bf16.h>

typedef __attribute__((ext_vector_type(8))) short short8;
typedef __attribute__((ext_vector_type(4))) float f32x4;

#define XT_IMG_BYTES (66*66*256*2)       // 2,230,272 per sample
#define XT_TOTAL_BYTES (32*XT_IMG_BYTES) // 71,368,704
#define WB_ROW_BYTES (2304*2)            // 4608
#define WB_OFF   (XT_TOTAL_BYTES)                 // Wbf16 [256][2304]   1,179,648 B
#define W2T_OFF  (WB_OFF + 256*WB_ROW_BYTES)      // W2T  [i][o] f32       262,144 B
#define SC_OFF   (W2T_OFF + 256*256*4)            // sc   [b][o] f32        32,768 B
#define YM_OFF   (SC_OFF  + 32*256*4)             // ymod [b][i] f32        32,768 B

static __device__ __forceinline__ void async16(void* lds, const void* g) {
  __builtin_amdgcn_global_load_lds((const __attribute__((address_space(1))) void*)g,
                                   (__attribute__((address_space(3))) void*)lds, 16, 0, 0);
}
static __device__ __forceinline__ ushort f2bf(float f) {
  __hip_bfloat16 h = __float2bfloat16(f);
  return *reinterpret_cast<ushort*>(&h);
}

// ---------------- zero ONLY the pad border of xT (4.3 MB) -----------------------
__global__ __launch_bounds__(256) void k_zeroborder(uint4* __restrict__ xT4) {
  const int b = blockIdx.x;
  const int t = threadIdx.x;
  const uint4 z = make_uint4(0u, 0u, 0u, 0u);
  uint4* base = xT4 + (size_t)b * (66 * 66 * 32);  // 32 uint4 per pixel
  uint4* r0  = base;
  uint4* r65 = base + (size_t)65 * 66 * 32;
  for (int i = t; i < 2112; i += 256) { r0[i] = z; r65[i] = z; }  // rows 0 & 65
  for (int i = t; i < 2048; i += 256) {                            // cols 0 & 65
    int r = (i >> 5) + 1, c = i & 31;
    base[((size_t)r * 66 + 0)  * 32 + c] = z;
    base[((size_t)r * 66 + 65) * 32 + c] = z;
  }
}

// ------- W [o][i][9] fp32 -> Wb [o][r*256+i] bf16  +  W2T [i][o] = sum_r W^2 ----
__global__ __launch_bounds__(256) void k_wprep(const float* __restrict__ W,
                                               ushort* __restrict__ Wb,
                                               float* __restrict__ W2T) {
  const int o = blockIdx.x, i = threadIdx.x;
  const float* wp = W + (size_t)(o * 256 + i) * 9;
  float wr[9], ss = 0.f;
#pragma unroll
  for (int r = 0; r < 9; ++r) { wr[r] = wp[r]; ss += wr[r] * wr[r]; }
  W2T[i * 256 + o] = ss;
  ushort* op = Wb + (size_t)o * 2304 + i;
#pragma unroll
  for (int r = 0; r < 9; ++r) op[r * 256] = f2bf(wr[r]);
}

// ------- sc[b][o] = rsqrt(sum_i W2[o][i]*(y[b][i]+1)^2 + eps); ymod[b][i]=y+1 ---
__global__ __launch_bounds__(256) void k_scale(const float* __restrict__ y,
                                               const float* __restrict__ W2T,
                                               float* __restrict__ sc,
                                               float* __restrict__ ymod) {
  __shared__ float ym2[256];
  const int b = blockIdx.x, t = threadIdx.x;
  const float ym = y[b * 256 + t] + 1.0f;
  ymod[b * 256 + t] = ym;
  ym2[t] = ym * ym;
  __syncthreads();
  float acc = 0.f;
#pragma unroll 8
  for (int i = 0; i < 256; ++i) acc += W2T[i * 256 + t] * ym2[i];
  sc[b * 256 + t] = rsqrtf(acc + 1e-8f);
}

// -- x [b][c][h][w] fp32 -> xT [b][h+1][w+1][c] bf16, modulated by ymod[b][c] ----
__global__ __launch_bounds__(256) void k_xpose(const float* __restrict__ x,
                                               const float* __restrict__ ymod,
                                               ushort* __restrict__ xT) {
  __shared__ float lds[64][65];
  __shared__ float ym_s[64];
  const int bx = blockIdx.x;
  const int b  = bx >> 6;
  const int hg = (bx >> 2) & 15;     // group of 4 rows
  const int c0 = (bx & 3) << 6;
  const int t  = threadIdx.x;
  if (t < 64) ym_s[t] = ymod[b * 256 + c0 + t];
  const int tw = t & 63, tg = t >> 6;
  const int q  = t & 15, w0 = t >> 4;
  for (int hh = 0; hh < 4; ++hh) {
    const int h = hg * 4 + hh;
    __syncthreads();  // LDS reuse + ym_s ready
    const float* xp = x + (size_t)(b * 256 + c0) * 4096 + h * 64 + tw;
#pragma unroll
    for (int j = 0; j < 16; ++j) {
      int il = j * 4 + tg;
      lds[il][tw] = xp[(size_t)il * 4096];
    }
    __syncthreads();
    ushort* op = xT + (size_t)b * (66 * 66 * 256) + ((size_t)(h + 1) * 66 + 1) * 256 + c0;
#pragma unroll
    for (int j = 0; j < 4; ++j) {
      const int wl = j * 16 + w0;
      ushort4 v;
      v.x = f2bf(lds[4 * q + 0][wl] * ym_s[4 * q + 0]);
      v.y = f2bf(lds[4 * q + 1][wl] * ym_s[4 * q + 1]);
      v.z = f2bf(lds[4 * q + 2][wl] * ym_s[4 * q + 2]);
      v.w = f2bf(lds[4 * q + 3][wl] * ym_s[4 * q + 3]);
      *(ushort4*)(op + (size_t)wl * 256 + 4 * q) = v;
    }
  }
}

// ---------------- implicit-GEMM conv: out[b][o][n] = sc[b][o]*sum_k Wb*xm + bias
// A (Wb) is sample-independent: 1.18 MB, L2-resident on every XCD.
__global__ __launch_bounds__(256, 2) void k_gemm(const ushort* __restrict__ Wb,
                                                 const ushort* __restrict__ xT,
                                                 const float* __restrict__ sc,
                                                 const float* __restrict__ bias,
                                                 float* __restrict__ out) {
  __shared__ ushort ldsA[128 * 32];  // [o_row 0..127][k 0..31]
  __shared__ ushort ldsB[128 * 32];  // [n_row 0..127][k 0..31]
  const int t = threadIdx.x;
  const int bx = blockIdx.x;
  const int xcd = bx & 7;            // hw round-robins consecutive blocks over XCDs
  const int idx = bx >> 3;           // 0..255
  const int b   = xcd + ((idx >> 6) << 3);  // 4 samples per XCD
  const int rem = idx & 63;
  const int o0 = (rem & 1) << 7;
  const int tn = rem >> 1;
  const int n0 = tn << 7;
  const int h0 = tn << 1;
  const int l = t & 63, w = t >> 6;
  const int ln = l & 15, kq = l >> 4;
  const int wm = w >> 1, wn = w & 1;

  const char* gA = (const char*)Wb + (size_t)(o0 + (t >> 2)) * WB_ROW_BYTES + (t & 3) * 16;
  const char* xTb = (const char*)xT + (size_t)b * XT_IMG_BYTES + (t & 3) * 16;
  const int wl = (t >> 2) & 63;

  f32x4 acc[4][4];
  const f32x4 z4 = {0.f, 0.f, 0.f, 0.f};
#pragma unroll
  for (int i = 0; i < 4; ++i)
#pragma unroll
    for (int j = 0; j < 4; ++j) acc[i][j] = z4;

  ushort* lA = ldsA + t * 8;
  ushort* lB = ldsB + t * 8;
  const ushort* rA = ldsA + (wm * 64 + ln) * 32 + kq * 8;
  const ushort* rB = ldsB + (wn * 64 + ln) * 32 + kq * 8;

#pragma unroll 1
  for (int r = 0; r < 9; ++r) {
    const int kh = r / 3, kw = r % 3;
    const char* gB = xTb + (((h0 + kh) * 66 + wl + kw) * 512);
#pragma unroll 1
    for (int s = 0; s < 8; ++s) {
      async16(lA, gA);
      async16(lA + 2048, gA + 64 * WB_ROW_BYTES);
      async16(lB, gB);
      async16(lB + 2048, gB + 66 * 512);
      asm volatile("s_waitcnt vmcnt(0)" ::: "memory");
      __syncthreads();
      short8 af[4], bf[4];
#pragma unroll
      for (int mi = 0; mi < 4; ++mi) af[mi] = *(const short8*)(rA + mi * 16 * 32);
#pragma unroll
      for (int ni = 0; ni < 4; ++ni) bf[ni] = *(const short8*)(rB + ni * 16 * 32);
#pragma unroll
      for (int mi = 0; mi < 4; ++mi)
#pragma unroll
        for (int ni = 0; ni < 4; ++ni)
          acc[mi][ni] = __builtin_amdgcn_mfma_f32_16x16x32_bf16(af[mi], bf[ni], acc[mi][ni], 0, 0, 0);
      __syncthreads();
      gA += 64;  // advance K by 32 bf16
      gB += 64;
    }
  }

  // epilogue: row = o (row=(lane>>4)*4+reg), col = n (lane&15); scale + bias
  float* outB = out + (size_t)(b * 256 + o0 + wm * 64) * 4096 + n0 + wn * 64 + ln;
  const float* scB = sc + b * 256 + o0 + wm * 64;
#pragma unroll
  for (int mi = 0; mi < 4; ++mi) {
#pragma unroll
    for (int rg = 0; rg < 4; ++rg) {
      const int orow = mi * 16 + kq * 4 + rg;
      const float scv = scB[orow];
      const float bv = bias[o0 + wm * 64 + orow];
      float* po = outB + (size_t)orow * 4096;
#pragma unroll
      for (int ni = 0; ni < 4; ++ni) po[ni * 16] = acc[mi][ni][rg] * scv + bv;
    }
  }
}

extern "C" void kernel_launch(void* const* d_in, const int* in_sizes, int n_in,
                              void* d_out, int out_size, void* d_ws, size_t ws_size,
                              hipStream_t stream) {
  const float* x    = (const float*)d_in[0];   // [32,256,64,64]
  const float* y    = (const float*)d_in[1];   // [32,256]
  const float* W    = (const float*)d_in[2];   // [256,256,3,3]
  const float* bias = (const float*)d_in[3];   // [256]
  float* out = (float*)d_out;                  // [32,256,64,64]

  char* ws = (char*)d_ws;
  ushort* xT   = (ushort*)ws;
  ushort* Wb   = (ushort*)(ws + WB_OFF);
  float*  W2T  = (float*) (ws + W2T_OFF);
  float*  sc   = (float*) (ws + SC_OFF);
  float*  ymod = (float*) (ws + YM_OFF);

  k_zeroborder<<<32,       256, 0, stream>>>((uint4*)d_ws);
  k_wprep     <<<256,      256, 0, stream>>>(W, Wb, W2T);
  k_scale     <<<32,       256, 0, stream>>>(y, W2T, sc, ymod);
  k_xpose     <<<32 * 64,  256, 0, stream>>>(x, ymod, xT);
  k_gemm      <<<32 * 64,  256, 0, stream>>>(Wb, xT, sc, bias, out);
}